// Round 12
// baseline (47.949 us; speedup 1.0000x reference)
//
#include <hip/hip_runtime.h>

// MVDR beamformer: STFT(+out-zero) -> causal PSD (DPP scan) + Souden MVDR (LDL^H) -> fused iSTFT+OLA (atomic)
static constexpr int NFFT = 4096;
static constexpr int HOP  = 1024;
static constexpr int NF   = 2049;   // rfft bins
static constexpr int NT   = 29;     // frames
static constexpr int NS   = 32768;  // samples per channel
static constexpr int NB   = 2;      // batch
static constexpr int NSrc = 2;      // sources
static constexpr int NC   = 4;      // channels
static constexpr int NBS  = NB * NSrc;
static constexpr int FCHUNKS = (NF + 7) / 8;  // 257 f-chunks of 8 per block

#define PI_F     3.14159265358979323846f
#define TWO_PI_F 6.28318530717958647692f

// LDS padding: one extra float every 16 -> breaks all power-of-2 stride conflicts
#define IDX(a) ((a) + ((a) >> 4))
static constexpr int LDSN = 2048 + 128;  // padded length

__device__ inline float2 cmul(float2 a, float2 b) {
    return make_float2(a.x * b.x - a.y * b.y, a.x * b.y + a.y * b.x);
}
// a * conj(b)
__device__ inline float2 cmulc(float2 a, float2 b) {
    return make_float2(a.x * b.x + a.y * b.y, a.y * b.x - a.x * b.y);
}

// DPP-shifted source (0 for masked/out-of-range lanes): pure-VALU scan step.
template <int CTRL, int RMASK>
__device__ __forceinline__ float dpp0(float x) {
    return __int_as_float(__builtin_amdgcn_update_dpp(
        0, __float_as_int(x), CTRL, RMASK, 0xF, true));
}

// ---------------------------------------------------------------------------
// 4- and 8-point DFT building blocks. DIR=-1 forward (e^{-i}), +1 inverse.
// ---------------------------------------------------------------------------
template <int DIR>
__device__ inline void fft4v(float2 v[4]) {
    float2 t0 = make_float2(v[0].x + v[2].x, v[0].y + v[2].y);
    float2 t1 = make_float2(v[0].x - v[2].x, v[0].y - v[2].y);
    float2 t2 = make_float2(v[1].x + v[3].x, v[1].y + v[3].y);
    float2 t3 = make_float2(v[1].x - v[3].x, v[1].y - v[3].y);
    v[0] = make_float2(t0.x + t2.x, t0.y + t2.y);
    v[2] = make_float2(t0.x - t2.x, t0.y - t2.y);
    if (DIR < 0) {
        v[1] = make_float2(t1.x + t3.y, t1.y - t3.x);
        v[3] = make_float2(t1.x - t3.y, t1.y + t3.x);
    } else {
        v[1] = make_float2(t1.x - t3.y, t1.y + t3.x);
        v[3] = make_float2(t1.x + t3.y, t1.y - t3.x);
    }
}

template <int DIR>
__device__ inline void fft8v(float2 v[8]) {
    float2 e[4] = { v[0], v[2], v[4], v[6] };
    float2 o[4] = { v[1], v[3], v[5], v[7] };
    fft4v<DIR>(e);
    fft4v<DIR>(o);
    const float c = 0.70710678118654752f;
    float2 o0 = o[0], o1, o2, o3;
    if (DIR < 0) {
        o1 = make_float2(c * (o[1].x + o[1].y), c * (o[1].y - o[1].x));
        o2 = make_float2(o[2].y, -o[2].x);
        o3 = make_float2(c * (o[3].y - o[3].x), -c * (o[3].x + o[3].y));
    } else {
        o1 = make_float2(c * (o[1].x - o[1].y), c * (o[1].y + o[1].x));
        o2 = make_float2(-o[2].y, o[2].x);
        o3 = make_float2(-c * (o[3].x + o[3].y), c * (o[3].x - o[3].y));
    }
    v[0] = make_float2(e[0].x + o0.x, e[0].y + o0.y);
    v[4] = make_float2(e[0].x - o0.x, e[0].y - o0.y);
    v[1] = make_float2(e[1].x + o1.x, e[1].y + o1.y);
    v[5] = make_float2(e[1].x - o1.x, e[1].y - o1.y);
    v[2] = make_float2(e[2].x + o2.x, e[2].y + o2.y);
    v[6] = make_float2(e[2].x - o2.x, e[2].y - o2.y);
    v[3] = make_float2(e[3].x + o3.x, e[3].y + o3.y);
    v[7] = make_float2(e[3].x - o3.x, e[3].y - o3.y);
}

// ---------------------------------------------------------------------------
// Stockham radix-8 stage: src -> dst, 256 threads, one butterfly each.
// Twiddle powers via depth-3 tree.
// ---------------------------------------------------------------------------
template <int DIR, int NSs>
__device__ inline void stage8(const float* __restrict__ reS, const float* __restrict__ imS,
                              float* __restrict__ reD, float* __restrict__ imD, int tid) {
    int j = tid;
    float2 v[8];
    #pragma unroll
    for (int r = 0; r < 8; ++r) {
        int a = IDX(j + (r << 8));
        v[r] = make_float2(reS[a], imS[a]);
    }
    if (NSs > 1) {
        float ang = (float)DIR * (TWO_PI_F / (8.0f * (float)NSs)) * (float)(j & (NSs - 1));
        float2 w1; __sincosf(ang, &w1.y, &w1.x);
        float2 w2 = cmul(w1, w1);
        float2 w3 = cmul(w2, w1);
        float2 w4 = cmul(w2, w2);
        float2 w5 = cmul(w3, w2);
        float2 w6 = cmul(w3, w3);
        float2 w7 = cmul(w4, w3);
        v[1] = cmul(v[1], w1);
        v[2] = cmul(v[2], w2);
        v[3] = cmul(v[3], w3);
        v[4] = cmul(v[4], w4);
        v[5] = cmul(v[5], w5);
        v[6] = cmul(v[6], w6);
        v[7] = cmul(v[7], w7);
    }
    fft8v<DIR>(v);
    int idxD = ((j & ~(NSs - 1)) << 3) + (j & (NSs - 1));
    #pragma unroll
    for (int r = 0; r < 8; ++r) {
        int a = IDX(idxD + r * NSs);
        reD[a] = v[r].x;
        imD[a] = v[r].y;
    }
}

// Final radix-4 stage, NS=512: threads handle j = tid and tid+256. Natural order.
template <int DIR>
__device__ inline void stage4_512(const float* __restrict__ reS, const float* __restrict__ imS,
                                  float* __restrict__ reD, float* __restrict__ imD, int tid) {
    #pragma unroll
    for (int h = 0; h < 2; ++h) {
        int j = tid + (h << 8);
        float2 v[4];
        #pragma unroll
        for (int r = 0; r < 4; ++r) {
            int a = IDX(j + (r << 9));
            v[r] = make_float2(reS[a], imS[a]);
        }
        float ang = (float)DIR * (TWO_PI_F / 2048.0f) * (float)j;
        float2 w1; __sincosf(ang, &w1.y, &w1.x);
        float2 w2 = cmul(w1, w1);
        float2 w3 = cmul(w2, w1);
        v[1] = cmul(v[1], w1);
        v[2] = cmul(v[2], w2);
        v[3] = cmul(v[3], w3);
        fft4v<DIR>(v);
        #pragma unroll
        for (int r = 0; r < 4; ++r) {
            int a = IDX(j + (r << 9));
            reD[a] = v[r].x;
            imD[a] = v[r].y;
        }
    }
}

template <int DIR>
__device__ inline void fft2048(float* reA, float* imA, float* reB, float* imB, int tid) {
    stage8<DIR, 1>(reA, imA, reB, imB, tid);  __syncthreads();
    stage8<DIR, 8>(reB, imB, reA, imA, tid);  __syncthreads();
    stage8<DIR, 64>(reA, imA, reB, imB, tid); __syncthreads();
    stage4_512<DIR>(reB, imB, reA, imA, tid); __syncthreads();
}

// ---------------------------------------------------------------------------
// STFT: one block per frame (696 total). Also zeroes `out` (grid-stride
// float4) so the fused iSTFT+OLA kernel can accumulate with atomics.
// ---------------------------------------------------------------------------
__global__ __launch_bounds__(256) void stft_kernel(
    const float* __restrict__ x, const float* __restrict__ s,
    float2* __restrict__ Xs, float2* __restrict__ Ss,
    float* __restrict__ out) {
    __shared__ float reA[LDSN], imA[LDSN], reB[LDSN], imB[LDSN];
    int tid = threadIdx.x;
    int fid = blockIdx.x;

    // zero output (consumed by istft_ola atomics; stream-ordered before it)
    float4* o4 = (float4*)out;
    const int n4 = (NBS * NC * NS) >> 2;
    for (int i = fid * 256 + tid; i < n4; i += gridDim.x * 256)
        o4[i] = make_float4(0.f, 0.f, 0.f, 0.f);

    const float* src;
    float2* dst;
    if (fid < NB * NC * NT) {
        int b = fid / (NC * NT);
        int r = fid % (NC * NT);
        int c = r / NT;
        int t = r % NT;
        src = x + (size_t)((b * NC + c) * NS + t * HOP);
        dst = Xs + (size_t)((b * NC + c) * NT + t) * NF;
    } else {
        int g  = fid - NB * NC * NT;
        int bs = g / (NC * NT);
        int r  = g % (NC * NT);
        int c  = r / NT;
        int t  = r % NT;
        src = s + (size_t)((bs * NC + c) * NS + t * HOP);
        dst = Ss + (size_t)((bs * NC + c) * NT + t) * NF;
    }
    const float2* s2 = (const float2*)src;
    for (int n = tid; n < 2048; n += 256) {
        float2 v = s2[n];
        float we = __sinf((float)n * (PI_F / 2048.0f));
        float wo = __sinf((float)(2 * n + 1) * (PI_F / 4096.0f));
        int a = IDX(n);
        reA[a] = v.x * we;
        imA[a] = v.y * wo;
    }
    __syncthreads();
    fft2048<-1>(reA, imA, reB, imB, tid);
    for (int k = tid; k <= 1024; k += 256) {
        int a1 = IDX(k);
        int a2 = IDX((2048 - k) & 2047);
        float2 Za = make_float2(reA[a1], imA[a1]);
        float2 Zb = make_float2(reA[a2], imA[a2]);
        if (k == 0) {
            dst[0]    = make_float2(Za.x + Za.y, 0.f);
            dst[2048] = make_float2(Za.x - Za.y, 0.f);
        } else {
            float2 Ze = make_float2(0.5f * (Za.x + Zb.x),  0.5f * (Za.y - Zb.y));
            float2 Zo = make_float2(0.5f * (Za.y + Zb.y), -0.5f * (Za.x - Zb.x));
            float ang = -(PI_F / 2048.0f) * (float)k;
            float2 W; __sincosf(ang, &W.y, &W.x);
            float2 WZo = cmul(W, Zo);
            dst[k] = make_float2(Ze.x + WZo.x, Ze.y + WZo.y);
            if (k < 1024)
                dst[2048 - k] = make_float2(Ze.x - WZo.x, -(Ze.y - WZo.y));
        }
    }
}

// ---------------------------------------------------------------------------
// Fused MVDR (byte-identical math to round 9/11). Block = (bs, 8 f).
// ---------------------------------------------------------------------------
__global__ __launch_bounds__(256, 1) void mvdr2_kernel(
    const float2* __restrict__ Xs, const float2* __restrict__ Ss,
    float2* __restrict__ Es) {
    __shared__ float2 ldsS[4][32][9];   // also reused as E-staging
    __shared__ float2 ldsX[4][32][9];
    int tid = threadIdx.x;
    int blk = blockIdx.x;
    int bs  = blk / FCHUNKS;
    int f0  = (blk % FCHUNKS) * 8;
    int b   = bs >> 1;

    for (int idx = tid; idx < 2048; idx += 256) {
        int fi = idx & 7;
        int tt = (idx >> 3) & 31;
        int q  = idx >> 8;       // 0..7
        int c  = q & 3;
        int f  = f0 + fi;
        float2 val = make_float2(0.f, 0.f);
        if (tt < NT && f < NF) {
            val = (q >= 4) ? Xs[(size_t)((b  * NC + c) * NT + tt) * NF + f]
                           : Ss[(size_t)((bs * NC + c) * NT + tt) * NF + f];
        }
        if (q >= 4) ldsX[c][tt][fi] = val; else ldsS[c][tt][fi] = val;
    }
    __syncthreads();

    int lane  = tid & 63;
    int wave  = tid >> 6;
    int t     = lane & 31;
    int fpair = lane >> 5;
    int fi    = wave * 2 + fpair;

    float2 Sv[4], Xv[4], Nv[4];
    #pragma unroll
    for (int c = 0; c < 4; ++c) {
        Sv[c] = ldsS[c][t][fi];
        Xv[c] = ldsX[c][t][fi];
        Nv[c] = make_float2(Xv[c].x - Sv[c].x, Xv[c].y - Sv[c].y);
    }

    float v[32];
    #pragma unroll
    for (int c = 0; c < 4; ++c) {
        v[c]      = Sv[c].x * Sv[c].x + Sv[c].y * Sv[c].y;
        v[16 + c] = Nv[c].x * Nv[c].x + Nv[c].y * Nv[c].y;
    }
    constexpr int PI6[6] = {0, 0, 0, 1, 1, 2};
    constexpr int PJ6[6] = {1, 2, 3, 2, 3, 3};
    #pragma unroll
    for (int p = 0; p < 6; ++p) {
        float2 d = cmulc(Sv[PI6[p]], Sv[PJ6[p]]);
        v[4 + 2 * p] = d.x; v[5 + 2 * p] = d.y;
        d = cmulc(Nv[PI6[p]], Nv[PJ6[p]]);
        v[20 + 2 * p] = d.x; v[21 + 2 * p] = d.y;
    }

    #pragma unroll
    for (int k = 0; k < 32; ++k) v[k] += dpp0<0x111, 0xF>(v[k]);
    #pragma unroll
    for (int k = 0; k < 32; ++k) v[k] += dpp0<0x112, 0xF>(v[k]);
    #pragma unroll
    for (int k = 0; k < 32; ++k) v[k] += dpp0<0x114, 0xF>(v[k]);
    #pragma unroll
    for (int k = 0; k < 32; ++k) v[k] += dpp0<0x118, 0xF>(v[k]);
    #pragma unroll
    for (int k = 0; k < 32; ++k) v[k] += dpp0<0x142, 0xA>(v[k]);

    float pd0 = v[0], pd1 = v[1], pd2 = v[2], pd3 = v[3];
    float2 po0 = make_float2(v[4],  v[5]);
    float2 po1 = make_float2(v[6],  v[7]);
    float2 po2 = make_float2(v[8],  v[9]);
    float2 po3 = make_float2(v[10], v[11]);
    float2 po4 = make_float2(v[12], v[13]);
    float2 po5 = make_float2(v[14], v[15]);
    float eps = (v[16] + v[17] + v[18] + v[19]) * 1e-7f + (float)(t + 1) * 1e-8f;
    float nd0 = v[16] + eps, nd1 = v[17] + eps, nd2 = v[18] + eps, nd3 = v[19] + eps;
    float2 no0 = make_float2(v[20], v[21]);
    float2 no1 = make_float2(v[22], v[23]);
    float2 no2 = make_float2(v[24], v[25]);
    float2 no3 = make_float2(v[26], v[27]);
    float2 no4 = make_float2(v[28], v[29]);
    float2 no5 = make_float2(v[30], v[31]);

    float D0 = nd0;
    float r0 = __builtin_amdgcn_rcpf(D0);
    float2 L10 = make_float2(no0.x * r0, -no0.y * r0);
    float2 L20 = make_float2(no1.x * r0, -no1.y * r0);
    float2 L30 = make_float2(no2.x * r0, -no2.y * r0);
    float D1 = nd1 - (L10.x * L10.x + L10.y * L10.y) * D0;
    float r1 = __builtin_amdgcn_rcpf(D1);
    float2 c10 = make_float2(D0 * L10.x, -D0 * L10.y);
    float2 tA = cmul(L20, c10);
    float2 L21 = make_float2((no3.x - tA.x) * r1, (-no3.y - tA.y) * r1);
    float2 tB = cmul(L30, c10);
    float2 L31 = make_float2((no4.x - tB.x) * r1, (-no4.y - tB.y) * r1);
    float D2 = nd2 - (L20.x * L20.x + L20.y * L20.y) * D0
                   - (L21.x * L21.x + L21.y * L21.y) * D1;
    float r2 = __builtin_amdgcn_rcpf(D2);
    float2 c20 = make_float2(D0 * L20.x, -D0 * L20.y);
    float2 c21 = make_float2(D1 * L21.x, -D1 * L21.y);
    float2 tC = cmul(L30, c20);
    float2 tD = cmul(L31, c21);
    float2 L32 = make_float2((no5.x - tC.x - tD.x) * r2, (-no5.y - tC.y - tD.y) * r2);
    float D3 = nd3 - (L30.x * L30.x + L30.y * L30.y) * D0
                   - (L31.x * L31.x + L31.y * L31.y) * D1
                   - (L32.x * L32.x + L32.y * L32.y) * D2;
    float r3 = __builtin_amdgcn_rcpf(D3);

    float2 u0 = Xv[0];
    float2 m0 = cmul(L10, u0);
    float2 u1 = make_float2(Xv[1].x - m0.x, Xv[1].y - m0.y);
    float2 m1 = cmul(L20, u0), m2 = cmul(L21, u1);
    float2 u2 = make_float2(Xv[2].x - m1.x - m2.x, Xv[2].y - m1.y - m2.y);
    float2 m3 = cmul(L30, u0), m4 = cmul(L31, u1), m5 = cmul(L32, u2);
    float2 u3 = make_float2(Xv[3].x - m3.x - m4.x - m5.x,
                            Xv[3].y - m3.y - m4.y - m5.y);
    float2 w0 = make_float2(u0.x * r0, u0.y * r0);
    float2 w1 = make_float2(u1.x * r1, u1.y * r1);
    float2 w2 = make_float2(u2.x * r2, u2.y * r2);
    float2 w3 = make_float2(u3.x * r3, u3.y * r3);
    float2 z3 = w3;
    float2 n0_ = cmulc(z3, L32);
    float2 z2 = make_float2(w2.x - n0_.x, w2.y - n0_.y);
    float2 n1_ = cmulc(z2, L21), n2_ = cmulc(z3, L31);
    float2 z1 = make_float2(w1.x - n1_.x - n2_.x, w1.y - n1_.y - n2_.y);
    float2 n3_ = cmulc(z1, L10), n4_ = cmulc(z2, L20), n5_ = cmulc(z3, L30);
    float2 z0 = make_float2(w0.x - n3_.x - n4_.x - n5_.x,
                            w0.y - n3_.y - n4_.y - n5_.y);

    float2 K10 = make_float2(-L10.x, -L10.y);
    float2 kk  = cmul(L21, L10);
    float2 K20 = make_float2(kk.x - L20.x, kk.y - L20.y);
    float2 K21 = make_float2(-L21.x, -L21.y);
    kk = cmul(L32, L21);
    float2 K31 = make_float2(kk.x - L31.x, kk.y - L31.y);
    float2 K32 = make_float2(-L32.x, -L32.y);
    float2 ka = cmul(K31, L10), kb = cmul(L32, L20);
    float2 K30 = make_float2(-L30.x - ka.x + kb.x, -L30.y - ka.y + kb.y);

    float q0 = pd0;
    float2 qm = cmul(K10, po0);
    float q1 = pd1 + (K10.x * K10.x + K10.y * K10.y) * pd0 + 2.0f * qm.x;
    qm = cmul(K20, po0);
    float s_a = qm.x * K21.x + qm.y * K21.y;
    qm = cmul(K20, po1);
    float s_b = qm.x;
    qm = cmul(K21, po3);
    float s_c = qm.x;
    float q2 = pd2 + (K20.x * K20.x + K20.y * K20.y) * pd0
                   + (K21.x * K21.x + K21.y * K21.y) * pd1
                   + 2.0f * (s_a + s_b + s_c);
    qm = cmul(K30, po0);
    float s1 = qm.x * K31.x + qm.y * K31.y;
    qm = cmul(K30, po1);
    float s2 = qm.x * K32.x + qm.y * K32.y;
    qm = cmul(K30, po2);
    float s3 = qm.x;
    qm = cmul(K31, po3);
    float s4 = qm.x * K32.x + qm.y * K32.y;
    qm = cmul(K31, po4);
    float s5 = qm.x;
    qm = cmul(K32, po5);
    float s6 = qm.x;
    float q3 = pd3 + (K30.x * K30.x + K30.y * K30.y) * pd0
                   + (K31.x * K31.x + K31.y * K31.y) * pd1
                   + (K32.x * K32.x + K32.y * K32.y) * pd2
                   + 2.0f * (s1 + s2 + s3 + s4 + s5 + s6);
    float tr = q0 * r0 + q1 * r1 + q2 * r2 + q3 * r3;
    float g  = __builtin_amdgcn_rcpf(tr + 1e-8f);

    float2 a0 = cmul(po0, z1), a1 = cmul(po1, z2), a2 = cmul(po2, z3);
    float2 e0 = make_float2(pd0 * z0.x + a0.x + a1.x + a2.x,
                            pd0 * z0.y + a0.y + a1.y + a2.y);
    a0 = cmulc(z0, po0); a1 = cmul(po3, z2); a2 = cmul(po4, z3);
    float2 e1 = make_float2(a0.x + pd1 * z1.x + a1.x + a2.x,
                            a0.y + pd1 * z1.y + a1.y + a2.y);
    a0 = cmulc(z0, po1); a1 = cmulc(z1, po3); a2 = cmul(po5, z3);
    float2 e2 = make_float2(a0.x + a1.x + pd2 * z2.x + a2.x,
                            a0.y + a1.y + pd2 * z2.y + a2.y);
    a0 = cmulc(z0, po2); a1 = cmulc(z1, po4); a2 = cmulc(z2, po5);
    float2 e3 = make_float2(a0.x + a1.x + a2.x + pd3 * z3.x,
                            a0.y + a1.y + a2.y + pd3 * z3.y);
    ldsS[0][t][fi] = make_float2(e0.x * g, e0.y * g);
    ldsS[1][t][fi] = make_float2(e1.x * g, e1.y * g);
    ldsS[2][t][fi] = make_float2(e2.x * g, e2.y * g);
    ldsS[3][t][fi] = make_float2(e3.x * g, e3.y * g);
    __syncthreads();

    for (int idx = tid; idx < 1024; idx += 256) {
        int fi2 = idx & 7;
        int tt  = (idx >> 3) & 31;
        int bo  = idx >> 8;
        int ff  = f0 + fi2;
        if (tt < NT && ff < NF)
            Es[(size_t)((bs * NC + bo) * NT + tt) * NF + ff] = ldsS[bo][tt][fi2];
    }
}

// ---------------------------------------------------------------------------
// Reciprocal of OLA window-squared denominator. Data-independent; interior
// samples (full 4-frame overlap) are exactly 2 (sin^2+cos^2 pairs).
// ---------------------------------------------------------------------------
__device__ inline float rwsq(int p) {
    int t1 = p >> 10;
    if (t1 > NT - 1) t1 = NT - 1;
    int t0 = (p >= NFFT) ? ((p - (NFFT - 1) + (HOP - 1)) >> 10) : 0;
    if (t1 - t0 == 3) return 0.5f;
    float wacc = 0.f;
    for (int t = t0; t <= t1; ++t) {
        float w = __sinf((float)(p - (t << 10)) * (PI_F / 4096.0f));
        wacc += w * w;
    }
    return 1.0f / fmaxf(wacc, 1e-8f);
}

// ---------------------------------------------------------------------------
// Fused iSTFT+OLA: one block per frame (464). Pack bins, inverse FFT, then
// atomically accumulate windowed, wsq-prenormalized samples into out.
// out[p] = sum_t contrib_t(p)/wsq(p) -- division distributes since wsq is
// data-independent. out is zeroed by stft_kernel (stream-ordered earlier).
// ---------------------------------------------------------------------------
__global__ __launch_bounds__(256) void istft_ola_kernel(
    const float2* __restrict__ Es, float* __restrict__ out) {
    __shared__ float reA[LDSN], imA[LDSN], reB[LDSN], imB[LDSN];
    int tid = threadIdx.x;
    int fid = blockIdx.x;
    int bs = fid / (NC * NT);
    int r  = fid % (NC * NT);
    int c  = r / NT;
    int t  = r % NT;
    const float2* src = Es + (size_t)((bs * NC + c) * NT + t) * NF;
    for (int k = tid; k <= 1024; k += 256) {
        float2 A = src[k];
        float2 B = src[2048 - k];
        float2 Ze = make_float2(0.5f * (A.x + B.x), 0.5f * (A.y - B.y));
        float2 D  = make_float2(0.5f * (A.x - B.x), 0.5f * (A.y + B.y));
        float ang = (PI_F / 2048.0f) * (float)k;
        float2 W; __sincosf(ang, &W.y, &W.x);
        float2 Zo = cmul(W, D);
        int a1 = IDX(k);
        reA[a1] = Ze.x - Zo.y;
        imA[a1] = Ze.y + Zo.x;
        if (k > 0 && k < 1024) {
            int a2 = IDX(2048 - k);
            reA[a2] = Ze.x + Zo.y;
            imA[a2] = -Ze.y + Zo.x;
        }
    }
    __syncthreads();
    fft2048<1>(reA, imA, reB, imB, tid);
    float* och = out + (size_t)(bs * NC + c) * NS;
    int base = t * HOP;
    for (int n = tid; n < 2048; n += 256) {
        int a  = IDX(n);
        int j0 = 2 * n, j1 = 2 * n + 1;
        float we = __sinf((float)n * (PI_F / 2048.0f)) * (1.0f / 2048.0f);
        float wo = __sinf((float)j1 * (PI_F / 4096.0f)) * (1.0f / 2048.0f);
        int p0 = base + j0, p1 = base + j1;
        atomicAdd(&och[p0], reA[a] * we * rwsq(p0));
        atomicAdd(&och[p1], imA[a] * wo * rwsq(p1));
    }
}

// ---------------------------------------------------------------------------
extern "C" void kernel_launch(void* const* d_in, const int* in_sizes, int n_in,
                              void* d_out, int out_size, void* d_ws, size_t ws_size,
                              hipStream_t stream) {
    const float* x = (const float*)d_in[0];  // (2,4,32768)
    const float* s = (const float*)d_in[1];  // (2,2,4,32768)
    float* out = (float*)d_out;              // (2,2,4,32768)

    const size_t XS_N = (size_t)NB  * NC * NT * NF;   // float2
    const size_t SS_N = (size_t)NBS * NC * NT * NF;   // float2
    float2* Xs = (float2*)d_ws;
    float2* Ss = Xs + XS_N;
    float2* Es = Ss + SS_N;

    stft_kernel<<<NB * NC * NT + NBS * NC * NT, 256, 0, stream>>>(x, s, Xs, Ss, out);

    mvdr2_kernel<<<NBS * FCHUNKS, 256, 0, stream>>>(Xs, Ss, Es);

    istft_ola_kernel<<<NBS * NC * NT, 256, 0, stream>>>(Es, out);
}

// Round 13
// 37.324 us; speedup vs baseline: 1.2846x; 1.2846x over previous
//
#include <hip/hip_runtime.h>

// MVDR beamformer pipeline: STFT -> causal PSD (DPP scan) -> Souden MVDR (LDL^H) -> beamform -> iSTFT -> OLA
static constexpr int NFFT = 4096;
static constexpr int HOP  = 1024;
static constexpr int NF   = 2049;   // rfft bins
static constexpr int NT   = 29;     // frames
static constexpr int NS   = 32768;  // samples per channel
static constexpr int NB   = 2;      // batch
static constexpr int NSrc = 2;      // sources
static constexpr int NC   = 4;      // channels
static constexpr int NBS  = NB * NSrc;
static constexpr int FCHUNKS = (NF + 7) / 8;  // 257 f-chunks of 8 per block

#define PI_F     3.14159265358979323846f
#define TWO_PI_F 6.28318530717958647692f

// LDS padding: one extra float every 16 -> breaks all power-of-2 stride conflicts
#define IDX(a) ((a) + ((a) >> 4))
static constexpr int LDSN = 2048 + 128;  // padded length

__device__ inline float2 cmul(float2 a, float2 b) {
    return make_float2(a.x * b.x - a.y * b.y, a.x * b.y + a.y * b.x);
}
// a * conj(b)
__device__ inline float2 cmulc(float2 a, float2 b) {
    return make_float2(a.x * b.x + a.y * b.y, a.y * b.x - a.x * b.y);
}

// DPP-shifted source (0 for masked/out-of-range lanes): pure-VALU scan step.
template <int CTRL, int RMASK>
__device__ __forceinline__ float dpp0(float x) {
    return __int_as_float(__builtin_amdgcn_update_dpp(
        0, __float_as_int(x), CTRL, RMASK, 0xF, true));
}

// ---------------------------------------------------------------------------
// 4- and 8-point DFT building blocks. DIR=-1 forward (e^{-i}), +1 inverse.
// ---------------------------------------------------------------------------
template <int DIR>
__device__ inline void fft4v(float2 v[4]) {
    float2 t0 = make_float2(v[0].x + v[2].x, v[0].y + v[2].y);
    float2 t1 = make_float2(v[0].x - v[2].x, v[0].y - v[2].y);
    float2 t2 = make_float2(v[1].x + v[3].x, v[1].y + v[3].y);
    float2 t3 = make_float2(v[1].x - v[3].x, v[1].y - v[3].y);
    v[0] = make_float2(t0.x + t2.x, t0.y + t2.y);
    v[2] = make_float2(t0.x - t2.x, t0.y - t2.y);
    if (DIR < 0) {
        v[1] = make_float2(t1.x + t3.y, t1.y - t3.x);
        v[3] = make_float2(t1.x - t3.y, t1.y + t3.x);
    } else {
        v[1] = make_float2(t1.x - t3.y, t1.y + t3.x);
        v[3] = make_float2(t1.x + t3.y, t1.y - t3.x);
    }
}

template <int DIR>
__device__ inline void fft8v(float2 v[8]) {
    float2 e[4] = { v[0], v[2], v[4], v[6] };
    float2 o[4] = { v[1], v[3], v[5], v[7] };
    fft4v<DIR>(e);
    fft4v<DIR>(o);
    const float c = 0.70710678118654752f;
    float2 o0 = o[0], o1, o2, o3;
    if (DIR < 0) {
        o1 = make_float2(c * (o[1].x + o[1].y), c * (o[1].y - o[1].x));
        o2 = make_float2(o[2].y, -o[2].x);
        o3 = make_float2(c * (o[3].y - o[3].x), -c * (o[3].x + o[3].y));
    } else {
        o1 = make_float2(c * (o[1].x - o[1].y), c * (o[1].y + o[1].x));
        o2 = make_float2(-o[2].y, o[2].x);
        o3 = make_float2(-c * (o[3].x + o[3].y), c * (o[3].x - o[3].y));
    }
    v[0] = make_float2(e[0].x + o0.x, e[0].y + o0.y);
    v[4] = make_float2(e[0].x - o0.x, e[0].y - o0.y);
    v[1] = make_float2(e[1].x + o1.x, e[1].y + o1.y);
    v[5] = make_float2(e[1].x - o1.x, e[1].y - o1.y);
    v[2] = make_float2(e[2].x + o2.x, e[2].y + o2.y);
    v[6] = make_float2(e[2].x - o2.x, e[2].y - o2.y);
    v[3] = make_float2(e[3].x + o3.x, e[3].y + o3.y);
    v[7] = make_float2(e[3].x - o3.x, e[3].y - o3.y);
}

// ---------------------------------------------------------------------------
// Stockham radix-8 stage: src -> dst, 256 threads, one butterfly each.
// Twiddle powers via depth-3 tree.
// ---------------------------------------------------------------------------
template <int DIR, int NSs>
__device__ inline void stage8(const float* __restrict__ reS, const float* __restrict__ imS,
                              float* __restrict__ reD, float* __restrict__ imD, int tid) {
    int j = tid;
    float2 v[8];
    #pragma unroll
    for (int r = 0; r < 8; ++r) {
        int a = IDX(j + (r << 8));
        v[r] = make_float2(reS[a], imS[a]);
    }
    if (NSs > 1) {
        float ang = (float)DIR * (TWO_PI_F / (8.0f * (float)NSs)) * (float)(j & (NSs - 1));
        float2 w1; __sincosf(ang, &w1.y, &w1.x);
        float2 w2 = cmul(w1, w1);
        float2 w3 = cmul(w2, w1);
        float2 w4 = cmul(w2, w2);
        float2 w5 = cmul(w3, w2);
        float2 w6 = cmul(w3, w3);
        float2 w7 = cmul(w4, w3);
        v[1] = cmul(v[1], w1);
        v[2] = cmul(v[2], w2);
        v[3] = cmul(v[3], w3);
        v[4] = cmul(v[4], w4);
        v[5] = cmul(v[5], w5);
        v[6] = cmul(v[6], w6);
        v[7] = cmul(v[7], w7);
    }
    fft8v<DIR>(v);
    int idxD = ((j & ~(NSs - 1)) << 3) + (j & (NSs - 1));
    #pragma unroll
    for (int r = 0; r < 8; ++r) {
        int a = IDX(idxD + r * NSs);
        reD[a] = v[r].x;
        imD[a] = v[r].y;
    }
}

// Final radix-4 stage, NS=512: threads handle j = tid and tid+256. Natural order.
template <int DIR>
__device__ inline void stage4_512(const float* __restrict__ reS, const float* __restrict__ imS,
                                  float* __restrict__ reD, float* __restrict__ imD, int tid) {
    #pragma unroll
    for (int h = 0; h < 2; ++h) {
        int j = tid + (h << 8);
        float2 v[4];
        #pragma unroll
        for (int r = 0; r < 4; ++r) {
            int a = IDX(j + (r << 9));
            v[r] = make_float2(reS[a], imS[a]);
        }
        float ang = (float)DIR * (TWO_PI_F / 2048.0f) * (float)j;
        float2 w1; __sincosf(ang, &w1.y, &w1.x);
        float2 w2 = cmul(w1, w1);
        float2 w3 = cmul(w2, w1);
        v[1] = cmul(v[1], w1);
        v[2] = cmul(v[2], w2);
        v[3] = cmul(v[3], w3);
        fft4v<DIR>(v);
        #pragma unroll
        for (int r = 0; r < 4; ++r) {
            int a = IDX(j + (r << 9));
            reD[a] = v[r].x;
            imD[a] = v[r].y;
        }
    }
}

template <int DIR>
__device__ inline void fft2048(float* reA, float* imA, float* reB, float* imB, int tid) {
    stage8<DIR, 1>(reA, imA, reB, imB, tid);  __syncthreads();
    stage8<DIR, 8>(reB, imB, reA, imA, tid);  __syncthreads();
    stage8<DIR, 64>(reA, imA, reB, imB, tid); __syncthreads();
    stage4_512<DIR>(reB, imB, reA, imA, tid); __syncthreads();
}

// ---------------------------------------------------------------------------
// STFT: one block per frame (696 total). Real-packing + 2048-pt FFT + unpack.
// ---------------------------------------------------------------------------
__global__ __launch_bounds__(256) void stft_kernel(
    const float* __restrict__ x, const float* __restrict__ s,
    float2* __restrict__ Xs, float2* __restrict__ Ss) {
    __shared__ float reA[LDSN], imA[LDSN], reB[LDSN], imB[LDSN];
    int tid = threadIdx.x;
    int fid = blockIdx.x;
    const float* src;
    float2* dst;
    if (fid < NB * NC * NT) {
        int b = fid / (NC * NT);
        int r = fid % (NC * NT);
        int c = r / NT;
        int t = r % NT;
        src = x + (size_t)((b * NC + c) * NS + t * HOP);
        dst = Xs + (size_t)((b * NC + c) * NT + t) * NF;
    } else {
        int g  = fid - NB * NC * NT;
        int bs = g / (NC * NT);
        int r  = g % (NC * NT);
        int c  = r / NT;
        int t  = r % NT;
        src = s + (size_t)((bs * NC + c) * NS + t * HOP);
        dst = Ss + (size_t)((bs * NC + c) * NT + t) * NF;
    }
    const float2* s2 = (const float2*)src;
    for (int n = tid; n < 2048; n += 256) {
        float2 v = s2[n];
        float we = __sinf((float)n * (PI_F / 2048.0f));
        float wo = __sinf((float)(2 * n + 1) * (PI_F / 4096.0f));
        int a = IDX(n);
        reA[a] = v.x * we;
        imA[a] = v.y * wo;
    }
    __syncthreads();
    fft2048<-1>(reA, imA, reB, imB, tid);
    for (int k = tid; k <= 1024; k += 256) {
        int a1 = IDX(k);
        int a2 = IDX((2048 - k) & 2047);
        float2 Za = make_float2(reA[a1], imA[a1]);
        float2 Zb = make_float2(reA[a2], imA[a2]);
        if (k == 0) {
            dst[0]    = make_float2(Za.x + Za.y, 0.f);
            dst[2048] = make_float2(Za.x - Za.y, 0.f);
        } else {
            float2 Ze = make_float2(0.5f * (Za.x + Zb.x),  0.5f * (Za.y - Zb.y));
            float2 Zo = make_float2(0.5f * (Za.y + Zb.y), -0.5f * (Za.x - Zb.x));
            float ang = -(PI_F / 2048.0f) * (float)k;
            float2 W; __sincosf(ang, &W.y, &W.x);
            float2 WZo = cmul(W, Zo);
            dst[k] = make_float2(Ze.x + WZo.x, Ze.y + WZo.y);
            if (k < 1024)
                dst[2048 - k] = make_float2(Ze.x - WZo.x, -(Ze.y - WZo.y));
        }
    }
}

// ---------------------------------------------------------------------------
// Fused MVDR, direct-gather version (no LDS, no barriers). Block = (bs, 8 f),
// 256 threads, lane = (fpair<<5)|t, fi = wave*2+fpair. The R4<->R5 controlled
// comparison showed direct t-stride gathers BEAT LDS transpose staging by
// ~2.7us (staging's 2048 LDS writes + 2 barriers + reads cost more than the
// coalescing gain; L2/L3 + TLP cover the gathers). Causal PSD via pure-VALU
// DPP segmented scan (unnormalized; eps = tr(Pn)*1e-7 + (t+1)*1e-8), then
// LDL^H solve, z = inv(pn)X, real trace via K = L^-1, e = g * ps @ z.
// ---------------------------------------------------------------------------
__global__ __launch_bounds__(256) void mvdr2_kernel(
    const float2* __restrict__ Xs, const float2* __restrict__ Ss,
    float2* __restrict__ Es) {
    int tid   = threadIdx.x;
    int blk   = blockIdx.x;
    int bs    = blk / FCHUNKS;
    int f0    = (blk % FCHUNKS) * 8;
    int b     = bs >> 1;
    int lane  = tid & 63;
    int wave  = tid >> 6;
    int t     = lane & 31;
    int fpair = lane >> 5;
    int fi    = wave * 2 + fpair;
    int f     = f0 + fi;
    bool valid = (t < NT) && (f < NF);

    float2 Sv[4], Xv[4], Nv[4];
    #pragma unroll
    for (int c = 0; c < 4; ++c) {
        if (valid) {
            Sv[c] = Ss[(size_t)((bs * NC + c) * NT + t) * NF + f];
            Xv[c] = Xs[(size_t)((b  * NC + c) * NT + t) * NF + f];
        } else {
            Sv[c] = make_float2(0.f, 0.f);
            Xv[c] = make_float2(0.f, 0.f);
        }
        Nv[c] = make_float2(Xv[c].x - Sv[c].x, Xv[c].y - Sv[c].y);
    }

    // 32 scan values: [0..3] ps diag, [4..15] ps off re/im, [16..19] pn diag,
    // [20..31] pn off re/im. Pairs: (0,1),(0,2),(0,3),(1,2),(1,3),(2,3).
    float v[32];
    #pragma unroll
    for (int c = 0; c < 4; ++c) {
        v[c]      = Sv[c].x * Sv[c].x + Sv[c].y * Sv[c].y;
        v[16 + c] = Nv[c].x * Nv[c].x + Nv[c].y * Nv[c].y;
    }
    constexpr int PI6[6] = {0, 0, 0, 1, 1, 2};
    constexpr int PJ6[6] = {1, 2, 3, 2, 3, 3};
    #pragma unroll
    for (int p = 0; p < 6; ++p) {
        float2 d = cmulc(Sv[PI6[p]], Sv[PJ6[p]]);
        v[4 + 2 * p] = d.x; v[5 + 2 * p] = d.y;
        d = cmulc(Nv[PI6[p]], Nv[PJ6[p]]);
        v[20 + 2 * p] = d.x; v[21 + 2 * p] = d.y;
    }

    // Segmented (32-lane) inclusive scan over t, pure VALU via DPP:
    // row_shr 1,2,4,8 within 16-lane rows, then row_bcast15 into odd rows.
    #pragma unroll
    for (int k = 0; k < 32; ++k) v[k] += dpp0<0x111, 0xF>(v[k]);
    #pragma unroll
    for (int k = 0; k < 32; ++k) v[k] += dpp0<0x112, 0xF>(v[k]);
    #pragma unroll
    for (int k = 0; k < 32; ++k) v[k] += dpp0<0x114, 0xF>(v[k]);
    #pragma unroll
    for (int k = 0; k < 32; ++k) v[k] += dpp0<0x118, 0xF>(v[k]);
    #pragma unroll
    for (int k = 0; k < 32; ++k) v[k] += dpp0<0x142, 0xA>(v[k]);

    // Unnormalized Hermitian entries.
    float pd0 = v[0], pd1 = v[1], pd2 = v[2], pd3 = v[3];
    float2 po0 = make_float2(v[4],  v[5]);
    float2 po1 = make_float2(v[6],  v[7]);
    float2 po2 = make_float2(v[8],  v[9]);
    float2 po3 = make_float2(v[10], v[11]);
    float2 po4 = make_float2(v[12], v[13]);
    float2 po5 = make_float2(v[14], v[15]);
    float eps = (v[16] + v[17] + v[18] + v[19]) * 1e-7f + (float)(t + 1) * 1e-8f;
    float nd0 = v[16] + eps, nd1 = v[17] + eps, nd2 = v[18] + eps, nd3 = v[19] + eps;
    float2 no0 = make_float2(v[20], v[21]);
    float2 no1 = make_float2(v[22], v[23]);
    float2 no2 = make_float2(v[24], v[25]);
    float2 no3 = make_float2(v[26], v[27]);
    float2 no4 = make_float2(v[28], v[29]);
    float2 no5 = make_float2(v[30], v[31]);

    // ---- LDL^H: pn = L D L^H (unit-lower L, real D). ----
    float D0 = nd0;
    float r0 = __builtin_amdgcn_rcpf(D0);
    float2 L10 = make_float2(no0.x * r0, -no0.y * r0);
    float2 L20 = make_float2(no1.x * r0, -no1.y * r0);
    float2 L30 = make_float2(no2.x * r0, -no2.y * r0);
    float D1 = nd1 - (L10.x * L10.x + L10.y * L10.y) * D0;
    float r1 = __builtin_amdgcn_rcpf(D1);
    float2 c10 = make_float2(D0 * L10.x, -D0 * L10.y);     // D0*conj(L10)
    float2 tA = cmul(L20, c10);
    float2 L21 = make_float2((no3.x - tA.x) * r1, (-no3.y - tA.y) * r1);
    float2 tB = cmul(L30, c10);
    float2 L31 = make_float2((no4.x - tB.x) * r1, (-no4.y - tB.y) * r1);
    float D2 = nd2 - (L20.x * L20.x + L20.y * L20.y) * D0
                   - (L21.x * L21.x + L21.y * L21.y) * D1;
    float r2 = __builtin_amdgcn_rcpf(D2);
    float2 c20 = make_float2(D0 * L20.x, -D0 * L20.y);
    float2 c21 = make_float2(D1 * L21.x, -D1 * L21.y);
    float2 tC = cmul(L30, c20);
    float2 tD = cmul(L31, c21);
    float2 L32 = make_float2((no5.x - tC.x - tD.x) * r2, (-no5.y - tC.y - tD.y) * r2);
    float D3 = nd3 - (L30.x * L30.x + L30.y * L30.y) * D0
                   - (L31.x * L31.x + L31.y * L31.y) * D1
                   - (L32.x * L32.x + L32.y * L32.y) * D2;
    float r3 = __builtin_amdgcn_rcpf(D3);

    // ---- z = inv(pn) X: forward L u = X, diag, back L^H z = w ----
    float2 u0 = Xv[0];
    float2 m0 = cmul(L10, u0);
    float2 u1 = make_float2(Xv[1].x - m0.x, Xv[1].y - m0.y);
    float2 m1 = cmul(L20, u0), m2 = cmul(L21, u1);
    float2 u2 = make_float2(Xv[2].x - m1.x - m2.x, Xv[2].y - m1.y - m2.y);
    float2 m3 = cmul(L30, u0), m4 = cmul(L31, u1), m5 = cmul(L32, u2);
    float2 u3 = make_float2(Xv[3].x - m3.x - m4.x - m5.x,
                            Xv[3].y - m3.y - m4.y - m5.y);
    float2 w0 = make_float2(u0.x * r0, u0.y * r0);
    float2 w1 = make_float2(u1.x * r1, u1.y * r1);
    float2 w2 = make_float2(u2.x * r2, u2.y * r2);
    float2 w3 = make_float2(u3.x * r3, u3.y * r3);
    float2 z3 = w3;
    float2 n0_ = cmulc(z3, L32);
    float2 z2 = make_float2(w2.x - n0_.x, w2.y - n0_.y);
    float2 n1_ = cmulc(z2, L21), n2_ = cmulc(z3, L31);
    float2 z1 = make_float2(w1.x - n1_.x - n2_.x, w1.y - n1_.y - n2_.y);
    float2 n3_ = cmulc(z1, L10), n4_ = cmulc(z2, L20), n5_ = cmulc(z3, L30);
    float2 z0 = make_float2(w0.x - n3_.x - n4_.x - n5_.x,
                            w0.y - n3_.y - n4_.y - n5_.y);

    // ---- K = L^-1 (unit lower) ----
    float2 K10 = make_float2(-L10.x, -L10.y);
    float2 kk  = cmul(L21, L10);
    float2 K20 = make_float2(kk.x - L20.x, kk.y - L20.y);
    float2 K21 = make_float2(-L21.x, -L21.y);
    kk = cmul(L32, L21);
    float2 K31 = make_float2(kk.x - L31.x, kk.y - L31.y);
    float2 K32 = make_float2(-L32.x, -L32.y);
    float2 ka = cmul(K31, L10), kb = cmul(L32, L20);
    float2 K30 = make_float2(-L30.x - ka.x + kb.x, -L30.y - ka.y + kb.y);

    // ---- tr = sum_i r_i * (K ps K^H)_ii (real quadratic forms) ----
    float q0 = pd0;
    float2 qm = cmul(K10, po0);
    float q1 = pd1 + (K10.x * K10.x + K10.y * K10.y) * pd0 + 2.0f * qm.x;
    qm = cmul(K20, po0);
    float s_a = qm.x * K21.x + qm.y * K21.y;   // Re(K20 po0 conj(K21))
    qm = cmul(K20, po1);
    float s_b = qm.x;
    qm = cmul(K21, po3);
    float s_c = qm.x;
    float q2 = pd2 + (K20.x * K20.x + K20.y * K20.y) * pd0
                   + (K21.x * K21.x + K21.y * K21.y) * pd1
                   + 2.0f * (s_a + s_b + s_c);
    qm = cmul(K30, po0);
    float s1 = qm.x * K31.x + qm.y * K31.y;
    qm = cmul(K30, po1);
    float s2 = qm.x * K32.x + qm.y * K32.y;
    qm = cmul(K30, po2);
    float s3 = qm.x;
    qm = cmul(K31, po3);
    float s4 = qm.x * K32.x + qm.y * K32.y;
    qm = cmul(K31, po4);
    float s5 = qm.x;
    qm = cmul(K32, po5);
    float s6 = qm.x;
    float q3 = pd3 + (K30.x * K30.x + K30.y * K30.y) * pd0
                   + (K31.x * K31.x + K31.y * K31.y) * pd1
                   + (K32.x * K32.x + K32.y * K32.y) * pd2
                   + 2.0f * (s1 + s2 + s3 + s4 + s5 + s6);
    float tr = q0 * r0 + q1 * r1 + q2 * r2 + q3 * r3;
    float g  = __builtin_amdgcn_rcpf(tr + 1e-8f);

    // ---- e = g * ps @ z (Hermitian matvec), direct scattered stores ----
    float2 a0 = cmul(po0, z1), a1 = cmul(po1, z2), a2 = cmul(po2, z3);
    float2 e0 = make_float2(pd0 * z0.x + a0.x + a1.x + a2.x,
                            pd0 * z0.y + a0.y + a1.y + a2.y);
    a0 = cmulc(z0, po0); a1 = cmul(po3, z2); a2 = cmul(po4, z3);
    float2 e1 = make_float2(a0.x + pd1 * z1.x + a1.x + a2.x,
                            a0.y + pd1 * z1.y + a1.y + a2.y);
    a0 = cmulc(z0, po1); a1 = cmulc(z1, po3); a2 = cmul(po5, z3);
    float2 e2 = make_float2(a0.x + a1.x + pd2 * z2.x + a2.x,
                            a0.y + a1.y + pd2 * z2.y + a2.y);
    a0 = cmulc(z0, po2); a1 = cmulc(z1, po4); a2 = cmulc(z2, po5);
    float2 e3 = make_float2(a0.x + a1.x + a2.x + pd3 * z3.x,
                            a0.y + a1.y + a2.y + pd3 * z3.y);
    if (valid) {
        Es[(size_t)((bs * NC + 0) * NT + t) * NF + f] = make_float2(e0.x * g, e0.y * g);
        Es[(size_t)((bs * NC + 1) * NT + t) * NF + f] = make_float2(e1.x * g, e1.y * g);
        Es[(size_t)((bs * NC + 2) * NT + t) * NF + f] = make_float2(e2.x * g, e2.y * g);
        Es[(size_t)((bs * NC + 3) * NT + t) * NF + f] = make_float2(e3.x * g, e3.y * g);
    }
}

// ---------------------------------------------------------------------------
// iSTFT: one block per frame (464). Pack bins, inverse FFT, window, write.
// ---------------------------------------------------------------------------
__global__ __launch_bounds__(256) void istft_kernel(
    const float2* __restrict__ Es, float* __restrict__ Fr) {
    __shared__ float reA[LDSN], imA[LDSN], reB[LDSN], imB[LDSN];
    int tid = threadIdx.x;
    int fid = blockIdx.x;
    int bs = fid / (NC * NT);
    int r  = fid % (NC * NT);
    int c  = r / NT;
    int t  = r % NT;
    const float2* src = Es + (size_t)((bs * NC + c) * NT + t) * NF;
    for (int k = tid; k <= 1024; k += 256) {
        float2 A = src[k];
        float2 B = src[2048 - k];
        float2 Ze = make_float2(0.5f * (A.x + B.x), 0.5f * (A.y - B.y));
        float2 D  = make_float2(0.5f * (A.x - B.x), 0.5f * (A.y + B.y));
        float ang = (PI_F / 2048.0f) * (float)k;
        float2 W; __sincosf(ang, &W.y, &W.x);
        float2 Zo = cmul(W, D);
        int a1 = IDX(k);
        reA[a1] = Ze.x - Zo.y;
        imA[a1] = Ze.y + Zo.x;
        if (k > 0 && k < 1024) {
            int a2 = IDX(2048 - k);
            reA[a2] = Ze.x + Zo.y;
            imA[a2] = -Ze.y + Zo.x;
        }
    }
    __syncthreads();
    fft2048<1>(reA, imA, reB, imB, tid);
    float2* d2 = (float2*)(Fr + (size_t)((bs * NC + c) * NT + t) * NFFT);
    for (int n = tid; n < 2048; n += 256) {
        int a = IDX(n);
        float we = __sinf((float)n * (PI_F / 2048.0f)) * (1.0f / 2048.0f);
        float wo = __sinf((float)(2 * n + 1) * (PI_F / 4096.0f)) * (1.0f / 2048.0f);
        d2[n] = make_float2(reA[a] * we, imA[a] * wo);
    }
}

// ---------------------------------------------------------------------------
// Overlap-add + window-squared normalization. One thread per output sample.
// Interior samples (full 4-frame overlap) have exact denominator 2.
// ---------------------------------------------------------------------------
__global__ __launch_bounds__(256) void ola_kernel(
    const float* __restrict__ Fr, float* __restrict__ out) {
    int idx = blockIdx.x * 256 + threadIdx.x;
    const int total = NBS * NC * NS;
    if (idx >= total) return;
    int p  = idx & (NS - 1);
    int ch = idx >> 15;
    int t1 = p >> 10;
    if (t1 > NT - 1) t1 = NT - 1;
    int t0 = (p >= NFFT) ? ((p - (NFFT - 1) + (HOP - 1)) >> 10) : 0;
    float acc = 0.f;
    for (int t = t0; t <= t1; ++t)
        acc += Fr[((size_t)(ch * NT + t) << 12) + (p - (t << 10))];
    float wacc;
    if (t1 - t0 == 3) {
        wacc = 2.0f;
    } else {
        wacc = 0.f;
        for (int t = t0; t <= t1; ++t) {
            float w = __sinf((float)(p - (t << 10)) * (PI_F / 4096.0f));
            wacc += w * w;
        }
    }
    out[idx] = acc / fmaxf(wacc, 1e-8f);
}

// ---------------------------------------------------------------------------
extern "C" void kernel_launch(void* const* d_in, const int* in_sizes, int n_in,
                              void* d_out, int out_size, void* d_ws, size_t ws_size,
                              hipStream_t stream) {
    const float* x = (const float*)d_in[0];  // (2,4,32768)
    const float* s = (const float*)d_in[1];  // (2,2,4,32768)
    float* out = (float*)d_out;              // (2,2,4,32768)

    const size_t XS_N = (size_t)NB  * NC * NT * NF;   // float2
    const size_t SS_N = (size_t)NBS * NC * NT * NF;   // float2
    float2* Xs = (float2*)d_ws;
    float2* Ss = Xs + XS_N;
    float2* Es = Ss + SS_N;
    float*  Fr = (float*)(Es + SS_N);

    stft_kernel<<<NB * NC * NT + NBS * NC * NT, 256, 0, stream>>>(x, s, Xs, Ss);

    mvdr2_kernel<<<NBS * FCHUNKS, 256, 0, stream>>>(Xs, Ss, Es);

    istft_kernel<<<NBS * NC * NT, 256, 0, stream>>>(Es, Fr);

    int ola_total = NBS * NC * NS;   // 524,288
    ola_kernel<<<(ola_total + 255) / 256, 256, 0, stream>>>(Fr, out);
}